// Round 7
// baseline (467.509 us; speedup 1.0000x reference)
//
#include <hip/hip_runtime.h>
#include <hip/hip_bf16.h>

#define NN 16000
#define NE 128000

typedef unsigned short u16;
typedef __attribute__((ext_vector_type(8))) short bf16x8;
typedef __attribute__((ext_vector_type(4))) float f32x4;

__device__ __forceinline__ float bf2f(u16 u) {
    unsigned int v = ((unsigned int)u) << 16;
    return __uint_as_float(v);
}
__device__ __forceinline__ u16 f2bf(float f) {
    unsigned int u = __float_as_uint(f);
    unsigned int r = u + 0x7FFF + ((u >> 16) & 1);
    return (u16)(r >> 16);
}
__device__ __forceinline__ float loadf(const void* p, size_t i, int bf) {
    return bf ? bf2f(((const u16*)p)[i]) : ((const float*)p)[i];
}

// ---- per-wave dtype detect (no barrier, deterministic): bf16=1, fp32=0 -----
// Fixed window: first 1024 u16 words of x. bf16 N(0,1): ~100% exponents in
// [100,140]; fp32-as-u16: ~58%. Threshold 850/1024.
__device__ __forceinline__ int detect_bf(const u16* __restrict__ xw) {
    int lane = threadIdx.x & 63;
    int c = 0;
    #pragma unroll
    for (int k = 0; k < 16; ++k) {
        unsigned int w = xw[lane * 16 + k];
        int e = (int)((w >> 7) & 0xFF);
        c += (e >= 100 && e <= 140) ? 1 : 0;
    }
    for (int m = 1; m < 64; m <<= 1) c += __shfl_xor(c, m, 64);
    return c >= 850;
}

// ---- per-wave edge-index layout detect: 1 = int64, 0 = int32 ---------------
// Fixed window: odd int32 words at indices 2j+1, j<1024 (safe both layouts).
__device__ __forceinline__ int detect_e64(const int* __restrict__ ei) {
    int lane = threadIdx.x & 63;
    int a = 0;
    #pragma unroll
    for (int k = 0; k < 16; ++k) a |= ei[2 * (lane * 16 + k) + 1];
    for (int m = 1; m < 64; m <<= 1) a |= __shfl_xor(a, m, 64);
    return a == 0;
}

// ---- pre1: blocks [0,250) cvt+clamp+hist; blocks [250,522) weight transpose
struct WDesc { const void* w; u16* wt; int K; int N; int off; int tile0; };
struct WTArgs { WDesc d[11]; };
__global__ __launch_bounds__(256) void pre1_kernel(const int* __restrict__ ei,
                                                   int* __restrict__ e32,
                                                   int* __restrict__ hist,
                                                   const u16* __restrict__ xw,
                                                   WTArgs args)
{
    int b = blockIdx.x;
    int tid = threadIdx.x;
    if (b < 250) {
        int e64 = detect_e64(ei);
        #pragma unroll
        for (int j = 0; j < 4; ++j) {
            int i = b * 1024 + j * 256 + tid;      // [0, 2E)
            int v = e64 ? ei[2 * i] : ei[i];
            v = v < 0 ? 0 : (v >= NN ? NN - 1 : v);
            e32[i] = v;
            if (i >= NE) atomicAdd(&hist[v], 1);
        }
        return;
    }
    int bf = detect_bf(xw);
    int i = 0;
    while (i < 10 && b >= args.d[i + 1].tile0) ++i;
    WDesc de = args.d[i];
    int lt = b - de.tile0;
    int tn = de.N >> 5;
    int tk = lt / tn, tc = lt % tn;
    int n = tc * 32 + (tid & 31);
    int k = tk * 32 + ((tid >> 5) << 2);
    u16* dp = de.wt + (size_t)n * de.K + k;
    #pragma unroll
    for (int j = 0; j < 4; ++j)
        dp[j] = f2bf(loadf(de.w, (size_t)de.off + (size_t)(k + j) * de.N + n, bf));
}

// ---- exclusive scan of hist -> offs[NN+1], copy -> cursor ------------------
__global__ __launch_bounds__(256) void scan_kernel(const int* __restrict__ hist,
                                                   int* __restrict__ offs,
                                                   int* __restrict__ cursor)
{
    __shared__ int wsum[4];
    __shared__ int carry_s;
    int tid = threadIdx.x, lane = tid & 63, w = tid >> 6;
    if (tid == 0) { carry_s = 0; offs[0] = 0; cursor[0] = 0; }
    __syncthreads();
    for (int c0 = 0; c0 < NN; c0 += 256) {
        int i = c0 + tid;
        int x = (i < NN) ? hist[i] : 0;
        #pragma unroll
        for (int o = 1; o < 64; o <<= 1) {
            int y = __shfl_up(x, o, 64);
            if (lane >= o) x += y;
        }
        if (lane == 63) wsum[w] = x;
        __syncthreads();
        if (tid == 0) {
            int s = 0;
            #pragma unroll
            for (int j = 0; j < 4; ++j) { int t2 = wsum[j]; wsum[j] = s; s += t2; }
        }
        __syncthreads();
        int incl = x + wsum[w] + carry_s;
        if (i < NN) { offs[i + 1] = incl; cursor[i + 1] = incl; }
        __syncthreads();
        if (tid == 255) carry_s = incl;
        __syncthreads();
    }
}

// ---- scatter: dst-sorted edge order ----------------------------------------
__global__ void scatter_kernel(const int* __restrict__ e32, int* __restrict__ cursor,
                               int* __restrict__ perm, int* __restrict__ ssrc,
                               int* __restrict__ sdst)
{
    int i = blockIdx.x * 256 + threadIdx.x;
    if (i >= NE) return;
    int d = e32[NE + i];
    int pos = atomicAdd(&cursor[d], 1);
    perm[pos] = i;
    ssrc[pos] = e32[i];
    sdst[pos] = d;
}

// ---- node_proj mega: LN(x) in-reg -> GEMM vs [Wq|Wk|Wv|Ws|Wg2] (640 cols) --
// Writes qkv [N,384] bf16 (phi on q), sbuf fp32 (+bs), gxs fp32 (+bg).
// Grid: N/16 blocks, 4 waves; wave w covers col-tiles [w*10, w*10+10).
__global__ __launch_bounds__(256) void node_proj_kernel(
    const void* __restrict__ x,
    const void* __restrict__ lng, const void* __restrict__ lnb,
    const u16* __restrict__ Wall,
    const void* __restrict__ bs, const void* __restrict__ bg,
    u16* __restrict__ qkv, float* __restrict__ sbuf, float* __restrict__ gxs)
{
    const int bf = detect_bf((const u16*)x);
    __shared__ float sg[128], sb[128];
    int tid = threadIdx.x;
    if (tid < 128) { sg[tid] = loadf(lng, tid, bf); sb[tid] = loadf(lnb, tid, bf); }
    __syncthreads();
    int wave = tid >> 6, lane = tid & 63;
    int quad = lane >> 4, l15 = lane & 15;
    int m0 = blockIdx.x * 16;

    // LN rows in registers (redundant per wave)
    float vbuf[32];
    float s = 0.f, sq = 0.f;
    size_t rbase = (size_t)(m0 + l15) * 128;
    #pragma unroll
    for (int kc = 0; kc < 4; ++kc) {
        int cb = kc * 32 + quad * 8;
        if (bf) {
            ushort4 p0 = *(const ushort4*)((const u16*)x + rbase + cb);
            ushort4 p1 = *(const ushort4*)((const u16*)x + rbase + cb + 4);
            vbuf[kc*8+0]=bf2f(p0.x); vbuf[kc*8+1]=bf2f(p0.y); vbuf[kc*8+2]=bf2f(p0.z); vbuf[kc*8+3]=bf2f(p0.w);
            vbuf[kc*8+4]=bf2f(p1.x); vbuf[kc*8+5]=bf2f(p1.y); vbuf[kc*8+6]=bf2f(p1.z); vbuf[kc*8+7]=bf2f(p1.w);
        } else {
            float4 p0 = *(const float4*)((const float*)x + rbase + cb);
            float4 p1 = *(const float4*)((const float*)x + rbase + cb + 4);
            vbuf[kc*8+0]=p0.x; vbuf[kc*8+1]=p0.y; vbuf[kc*8+2]=p0.z; vbuf[kc*8+3]=p0.w;
            vbuf[kc*8+4]=p1.x; vbuf[kc*8+5]=p1.y; vbuf[kc*8+6]=p1.z; vbuf[kc*8+7]=p1.w;
        }
        #pragma unroll
        for (int j = 0; j < 8; ++j) { s += vbuf[kc*8+j]; sq += vbuf[kc*8+j]*vbuf[kc*8+j]; }
    }
    s += __shfl_xor(s, 16, 64); sq += __shfl_xor(sq, 16, 64);
    s += __shfl_xor(s, 32, 64); sq += __shfl_xor(sq, 32, 64);
    float mu = s * (1.0f / 128.0f);
    float var = sq * (1.0f / 128.0f) - mu * mu;
    float rsx = rsqrtf(var + 1e-5f);
    bf16x8 afr[4];
    #pragma unroll
    for (int kc = 0; kc < 4; ++kc) {
        bf16x8 a;
        #pragma unroll
        for (int j = 0; j < 8; ++j) {
            int col = kc * 32 + quad * 8 + j;
            a[j] = (short)f2bf((vbuf[kc*8+j] - mu) * rsx * sg[col] + sb[col]);
        }
        afr[kc] = a;
    }

    f32x4 acc[10] = {};
    #pragma unroll
    for (int kc = 0; kc < 4; ++kc)
        #pragma unroll
        for (int tt = 0; tt < 10; ++tt) {
            int t = wave * 10 + tt;
            bf16x8 b = *(const bf16x8*)(Wall + (size_t)(t * 16 + l15) * 128 + kc * 32 + quad * 8);
            acc[tt] = __builtin_amdgcn_mfma_f32_16x16x32_bf16(afr[kc], b, acc[tt], 0, 0, 0);
        }
    #pragma unroll
    for (int tt = 0; tt < 10; ++tt) {
        int ct = (wave * 10 + tt) * 16 + l15;
        #pragma unroll
        for (int rg = 0; rg < 4; ++rg) {
            int row = m0 + quad * 4 + rg;
            float v = acc[tt][rg];
            if (ct < 384) {
                if (ct < 128) v = (v > 0.0f) ? v + 1.0f : expf(v);
                qkv[(size_t)row * 384 + ct] = f2bf(v);
            } else if (ct < 512) {
                int cs = ct - 384;
                sbuf[(size_t)row * 128 + cs] = v + loadf(bs, cs, bf);
            } else {
                int cg = ct - 512;
                gxs[(size_t)row * 128 + cg] = v + loadf(bg, cg, bf);
            }
        }
    }
}

// ---- Edge proj (dst-sorted, atomic-free) -----------------------------------
__global__ __launch_bounds__(256) void edge_proj_kernel(
    const void* __restrict__ r, const void* __restrict__ x,
    const void* __restrict__ lng, const void* __restrict__ lnb,
    const u16* __restrict__ Wkrt, const u16* __restrict__ Wvrt,
    const int* __restrict__ perm, const int* __restrict__ ssrc,
    const int* __restrict__ sdst,
    const u16* __restrict__ qkv,
    float* __restrict__ p_arr, u16* __restrict__ ve_s)
{
    const int bf = detect_bf((const u16*)x);
    __shared__ float sg[128], sb[128];
    int tid = threadIdx.x;
    if (tid < 128) { sg[tid] = loadf(lng, tid, bf); sb[tid] = loadf(lnb, tid, bf); }
    __syncthreads();
    int wave = tid >> 6, lane = tid & 63;
    int quad = lane >> 4, l15 = lane & 15;
    int e0 = blockIdx.x * 32 + (wave >> 1) * 16;
    int c0 = (wave & 1) * 64;

    int rrow = perm[e0 + l15];
    float vbuf[32];
    float s = 0.f, sq = 0.f;
    size_t rbase = (size_t)rrow * 128;
    #pragma unroll
    for (int kc = 0; kc < 4; ++kc) {
        int cb = kc * 32 + quad * 8;
        if (bf) {
            ushort4 p0 = *(const ushort4*)((const u16*)r + rbase + cb);
            ushort4 p1 = *(const ushort4*)((const u16*)r + rbase + cb + 4);
            vbuf[kc*8+0]=bf2f(p0.x); vbuf[kc*8+1]=bf2f(p0.y); vbuf[kc*8+2]=bf2f(p0.z); vbuf[kc*8+3]=bf2f(p0.w);
            vbuf[kc*8+4]=bf2f(p1.x); vbuf[kc*8+5]=bf2f(p1.y); vbuf[kc*8+6]=bf2f(p1.z); vbuf[kc*8+7]=bf2f(p1.w);
        } else {
            float4 p0 = *(const float4*)((const float*)r + rbase + cb);
            float4 p1 = *(const float4*)((const float*)r + rbase + cb + 4);
            vbuf[kc*8+0]=p0.x; vbuf[kc*8+1]=p0.y; vbuf[kc*8+2]=p0.z; vbuf[kc*8+3]=p0.w;
            vbuf[kc*8+4]=p1.x; vbuf[kc*8+5]=p1.y; vbuf[kc*8+6]=p1.z; vbuf[kc*8+7]=p1.w;
        }
        #pragma unroll
        for (int j = 0; j < 8; ++j) { s += vbuf[kc*8+j]; sq += vbuf[kc*8+j]*vbuf[kc*8+j]; }
    }
    s += __shfl_xor(s, 16, 64); sq += __shfl_xor(sq, 16, 64);
    s += __shfl_xor(s, 32, 64); sq += __shfl_xor(sq, 32, 64);
    float mu = s * (1.0f / 128.0f);
    float var = sq * (1.0f / 128.0f) - mu * mu;
    float rsx = rsqrtf(var + 1e-5f);
    bf16x8 afr[4];
    #pragma unroll
    for (int kc = 0; kc < 4; ++kc) {
        bf16x8 a;
        #pragma unroll
        for (int j = 0; j < 8; ++j) {
            int col = kc * 32 + quad * 8 + j;
            a[j] = (short)f2bf((vbuf[kc*8+j] - mu) * rsx * sg[col] + sb[col]);
        }
        afr[kc] = a;
    }

    f32x4 acck[4] = {};
    f32x4 accv[4] = {};
    #pragma unroll
    for (int kc = 0; kc < 4; ++kc) {
        int k0 = kc * 32;
        #pragma unroll
        for (int t = 0; t < 4; ++t) {
            bf16x8 bk = *(const bf16x8*)(Wkrt + (size_t)(c0 + t*16 + l15) * 128 + k0 + quad * 8);
            bf16x8 bv = *(const bf16x8*)(Wvrt + (size_t)(c0 + t*16 + l15) * 128 + k0 + quad * 8);
            acck[t] = __builtin_amdgcn_mfma_f32_16x16x32_bf16(afr[kc], bk, acck[t], 0, 0, 0);
            accv[t] = __builtin_amdgcn_mfma_f32_16x16x32_bf16(afr[kc], bv, accv[t], 0, 0, 0);
        }
    }

    int se[4], de[4];
    #pragma unroll
    for (int rg = 0; rg < 4; ++rg) {
        int e = e0 + quad * 4 + rg;
        se[rg] = ssrc[e]; de[rg] = sdst[e];
    }
    #pragma unroll
    for (int t = 0; t < 4; ++t) {
        int col = c0 + t * 16 + l15;
        float p_[4];
        #pragma unroll
        for (int rg = 0; rg < 4; ++rg) {
            float kv = acck[t][rg] + bf2f(qkv[(size_t)se[rg] * 384 + 128 + col]);
            kv = (kv > 0.0f) ? kv + 1.0f : expf(kv);
            float pm = kv * bf2f(qkv[(size_t)de[rg] * 384 + col]);
            pm += __shfl_xor(pm, 1, 64);
            pm += __shfl_xor(pm, 2, 64);
            pm += __shfl_xor(pm, 4, 64);
            pm += __shfl_xor(pm, 8, 64);
            p_[rg] = pm;
        }
        if (l15 == 0) {
            #pragma unroll
            for (int rg = 0; rg < 4; ++rg)
                p_arr[(size_t)(e0 + quad * 4 + rg) * 8 + (c0 >> 4) + t] = p_[rg];
        }
        #pragma unroll
        for (int rg = 0; rg < 4; ++rg) {
            float vv = accv[t][rg] + bf2f(qkv[(size_t)se[rg] * 384 + 256 + col]);
            ve_s[(size_t)(e0 + quad * 4 + rg) * 128 + col] = f2bf(vv);
        }
    }
}

// ---- Node accumulate: att = (sum p*ve) / max(sum p, eps) -------------------
__global__ __launch_bounds__(256) void node_acc_kernel(
    const float* __restrict__ p_arr, const u16* __restrict__ ve_s,
    const int* __restrict__ offs, u16* __restrict__ att)
{
    int n = blockIdx.x * 4 + (threadIdx.x >> 6);
    int lane = threadIdx.x & 63;
    int beg = offs[n], end = offs[n + 1];
    int h0 = lane >> 4, h1 = 4 + h0;
    float n0 = 0.f, n1 = 0.f, d0 = 0.f, d1 = 0.f;
    for (int e = beg; e < end; ++e) {
        float p0 = p_arr[(size_t)e * 8 + h0];
        float p1 = p_arr[(size_t)e * 8 + h1];
        float v0 = bf2f(ve_s[(size_t)e * 128 + lane]);
        float v1 = bf2f(ve_s[(size_t)e * 128 + lane + 64]);
        n0 += p0 * v0; n1 += p1 * v1;
        d0 += p0; d1 += p1;
    }
    att[(size_t)n * 128 + lane]      = f2bf(n0 / fmaxf(d0, 1e-6f));
    att[(size_t)n * 128 + lane + 64] = f2bf(n1 / fmaxf(d1, 1e-6f));
}

// ---- Gate mega: att@Wo -> @Wg1 (+gxs) -> gate -> post-LN -> xmid, ffp ------
__global__ __launch_bounds__(256) void gate_mega_kernel(
    const u16* __restrict__ att,
    const u16* __restrict__ Wo_t, const u16* __restrict__ Wg1_t,
    const float* __restrict__ gxs, const float* __restrict__ sbuf,
    const void* __restrict__ x,
    const void* __restrict__ g_po, const void* __restrict__ b_po,
    const void* __restrict__ g_fp, const void* __restrict__ b_fp,
    float* __restrict__ xmid, u16* __restrict__ ffp)
{
    const int bf = detect_bf((const u16*)x);
    __shared__ float lds[4][16][132];
    __shared__ float sgpo[128], sbpo[128], sgfp[128], sbfp[128];
    int tid = threadIdx.x;
    if (tid < 128) {
        sgpo[tid] = loadf(g_po, tid, bf);
        sbpo[tid] = loadf(b_po, tid, bf);
        sgfp[tid] = loadf(g_fp, tid, bf);
        sbfp[tid] = loadf(b_fp, tid, bf);
    }
    __syncthreads();
    int wave = tid >> 6, lane = tid & 63;
    int quad = lane >> 4, l15 = lane & 15;
    int m0 = blockIdx.x * 64 + wave * 16;

    bf16x8 afr[4];
    #pragma unroll
    for (int kc = 0; kc < 4; ++kc)
        afr[kc] = *(const bf16x8*)(att + (size_t)(m0 + l15) * 128 + kc * 32 + quad * 8);

    f32x4 acco[8] = {};
    #pragma unroll
    for (int kc = 0; kc < 4; ++kc)
        #pragma unroll
        for (int t = 0; t < 8; ++t) {
            bf16x8 b = *(const bf16x8*)(Wo_t + (size_t)(t*16 + l15) * 128 + kc*32 + quad*8);
            acco[t] = __builtin_amdgcn_mfma_f32_16x16x32_bf16(afr[kc], b, acco[t], 0, 0, 0);
        }
    #pragma unroll
    for (int t = 0; t < 8; ++t)
        #pragma unroll
        for (int rg = 0; rg < 4; ++rg)
            lds[wave][quad*4+rg][t*16+l15] = acco[t][rg];
    __syncthreads();
    bf16x8 afo[4];
    #pragma unroll
    for (int kc = 0; kc < 4; ++kc) {
        bf16x8 a;
        #pragma unroll
        for (int j = 0; j < 8; ++j)
            a[j] = (short)f2bf(lds[wave][l15][kc*32 + quad*8 + j]);
        afo[kc] = a;
    }
    f32x4 accg[8] = {};
    #pragma unroll
    for (int kc = 0; kc < 4; ++kc)
        #pragma unroll
        for (int t = 0; t < 8; ++t) {
            bf16x8 b = *(const bf16x8*)(Wg1_t + (size_t)(t*16 + l15) * 128 + kc*32 + quad*8);
            accg[t] = __builtin_amdgcn_mfma_f32_16x16x32_bf16(afo[kc], b, accg[t], 0, 0, 0);
        }
    float attn[8][4];
    float sv[4] = {0,0,0,0}, sqv[4] = {0,0,0,0};
    #pragma unroll
    for (int t = 0; t < 8; ++t) {
        int col = t * 16 + l15;
        #pragma unroll
        for (int rg = 0; rg < 4; ++rg) {
            int row = m0 + quad * 4 + rg;
            float gp = accg[t][rg] + gxs[(size_t)row * 128 + col];
            float gg = 1.0f / (1.0f + expf(-gp));
            float o = acco[t][rg];
            float a = o + gg * (sbuf[(size_t)row * 128 + col] - o);
            attn[t][rg] = a; sv[rg] += a; sqv[rg] += a * a;
        }
    }
    #pragma unroll
    for (int rg = 0; rg < 4; ++rg)
        for (int m = 1; m < 16; m <<= 1) {
            sv[rg] += __shfl_xor(sv[rg], m, 64);
            sqv[rg] += __shfl_xor(sqv[rg], m, 64);
        }
    float mu[4], rs[4];
    #pragma unroll
    for (int rg = 0; rg < 4; ++rg) {
        mu[rg] = sv[rg] * (1.0f / 128.0f);
        float var = sqv[rg] * (1.0f / 128.0f) - mu[rg] * mu[rg];
        rs[rg] = rsqrtf(var + 1e-5f);
    }
    float s2[4] = {0,0,0,0}, sq2[4] = {0,0,0,0};
    #pragma unroll
    for (int t = 0; t < 8; ++t) {
        int col = t * 16 + l15;
        #pragma unroll
        for (int rg = 0; rg < 4; ++rg) {
            int row = m0 + quad * 4 + rg;
            float xm = loadf(x, (size_t)row * 128 + col, bf)
                     + (attn[t][rg] - mu[rg]) * rs[rg] * sgpo[col] + sbpo[col];
            attn[t][rg] = xm;
            xmid[(size_t)row * 128 + col] = xm;
            s2[rg] += xm; sq2[rg] += xm * xm;
        }
    }
    #pragma unroll
    for (int rg = 0; rg < 4; ++rg)
        for (int m = 1; m < 16; m <<= 1) {
            s2[rg] += __shfl_xor(s2[rg], m, 64);
            sq2[rg] += __shfl_xor(sq2[rg], m, 64);
        }
    #pragma unroll
    for (int rg = 0; rg < 4; ++rg) {
        float mu2 = s2[rg] * (1.0f / 128.0f);
        float var2 = sq2[rg] * (1.0f / 128.0f) - mu2 * mu2;
        float rs2 = rsqrtf(var2 + 1e-5f);
        #pragma unroll
        for (int t = 0; t < 8; ++t) {
            int col = t * 16 + l15;
            int row = m0 + quad * 4 + rg;
            ffp[(size_t)row * 128 + col] =
                f2bf((attn[t][rg] - mu2) * rs2 * sgfp[col] + sbfp[col]);
        }
    }
}

// ---- FF mega: h1=gelu(ffp@W1+b1) -> h2=h1@W2+b2 -> out=xmid+LN(h2) ---------
__global__ __launch_bounds__(128) void ff_mega_kernel(
    const u16* __restrict__ ffp, const u16* __restrict__ W1_t, const void* __restrict__ b1,
    const u16* __restrict__ W2_t, const void* __restrict__ b2,
    const float* __restrict__ xmid, const void* __restrict__ x,
    const void* __restrict__ g_fo, const void* __restrict__ b_fo,
    void* __restrict__ outp)
{
    const int bf = detect_bf((const u16*)x);
    __shared__ __align__(16) u16 h1l[2][16][520];
    int tid = threadIdx.x;
    int wave = tid >> 6, lane = tid & 63;
    int quad = lane >> 4, l15 = lane & 15;
    int m0 = blockIdx.x * 32 + wave * 16;

    bf16x8 afr[4];
    const u16* ap = ffp + (size_t)(m0 + l15) * 128 + quad * 8;
    #pragma unroll
    for (int kc = 0; kc < 4; ++kc) afr[kc] = *(const bf16x8*)(ap + kc * 32);

    f32x4 acc1[32] = {};
    #pragma unroll
    for (int kc = 0; kc < 4; ++kc)
        #pragma unroll
        for (int t = 0; t < 32; ++t) {
            bf16x8 b = *(const bf16x8*)(W1_t + (size_t)(t*16 + l15) * 128 + kc*32 + quad*8);
            acc1[t] = __builtin_amdgcn_mfma_f32_16x16x32_bf16(afr[kc], b, acc1[t], 0, 0, 0);
        }
    #pragma unroll
    for (int t = 0; t < 32; ++t) {
        int col = t * 16 + l15;
        float bv = loadf(b1, col, bf);
        #pragma unroll
        for (int rg = 0; rg < 4; ++rg) {
            float v = acc1[t][rg] + bv;
            v = 0.5f * v * (1.0f + erff(v * 0.70710678118f));
            h1l[wave][quad * 4 + rg][col] = f2bf(v);
        }
    }
    __syncthreads();
    f32x4 acc2[8] = {};
    #pragma unroll
    for (int kc = 0; kc < 16; ++kc) {
        bf16x8 a = *(const bf16x8*)&h1l[wave][l15][kc * 32 + quad * 8];
        #pragma unroll
        for (int t = 0; t < 8; ++t) {
            bf16x8 b = *(const bf16x8*)(W2_t + (size_t)(t*16 + l15) * 512 + kc*32 + quad*8);
            acc2[t] = __builtin_amdgcn_mfma_f32_16x16x32_bf16(a, b, acc2[t], 0, 0, 0);
        }
    }
    float h2v[8][4];
    float sv[4] = {0,0,0,0}, sqv[4] = {0,0,0,0};
    #pragma unroll
    for (int t = 0; t < 8; ++t) {
        int col = t * 16 + l15;
        float bv = loadf(b2, col, bf);
        #pragma unroll
        for (int rg = 0; rg < 4; ++rg) {
            float v = acc2[t][rg] + bv;
            h2v[t][rg] = v; sv[rg] += v; sqv[rg] += v * v;
        }
    }
    #pragma unroll
    for (int rg = 0; rg < 4; ++rg)
        for (int m = 1; m < 16; m <<= 1) {
            sv[rg] += __shfl_xor(sv[rg], m, 64);
            sqv[rg] += __shfl_xor(sqv[rg], m, 64);
        }
    #pragma unroll
    for (int rg = 0; rg < 4; ++rg) {
        float mu = sv[rg] * (1.0f / 128.0f);
        float var = sqv[rg] * (1.0f / 128.0f) - mu * mu;
        float rs = rsqrtf(var + 1e-5f);
        int row = m0 + quad * 4 + rg;
        #pragma unroll
        for (int t = 0; t < 8; ++t) {
            int col = t * 16 + l15;
            float y = xmid[(size_t)row * 128 + col]
                    + (h2v[t][rg] - mu) * rs * loadf(g_fo, col, bf) + loadf(b_fo, col, bf);
            if (bf) ((u16*)outp)[(size_t)row * 128 + col] = f2bf(y);
            else    ((float*)outp)[(size_t)row * 128 + col] = y;
        }
    }
}

extern "C" void kernel_launch(void* const* d_in, const int* in_sizes, int n_in,
                              void* d_out, int out_size, void* d_ws, size_t ws_size,
                              hipStream_t stream)
{
    const int N = NN, E = NE;
    const void* x       = d_in[0];
    const void* r       = d_in[1];
    const int*  ei      = (const int*)d_in[2];
    const void* ln_x_g  = d_in[3];
    const void* ln_x_b  = d_in[4];
    const void* ln_r_g  = d_in[5];
    const void* ln_r_b  = d_in[6];
    const void* ln_po_g = d_in[7];
    const void* ln_po_b = d_in[8];
    const void* ln_fp_g = d_in[9];
    const void* ln_fp_b = d_in[10];
    const void* ln_fo_g = d_in[11];
    const void* ln_fo_b = d_in[12];
    const void* Wq      = d_in[13];
    const void* Wk      = d_in[14];
    const void* Wv      = d_in[15];
    const void* Wkr     = d_in[16];
    const void* Wvr     = d_in[17];
    const void* Wo      = d_in[18];
    const void* Wg      = d_in[19];
    const void* bg      = d_in[20];
    const void* Ws      = d_in[21];
    const void* bs      = d_in[22];
    const void* W1      = d_in[23];
    const void* b1      = d_in[24];
    const void* W2      = d_in[25];
    const void* b2      = d_in[26];

    // ---- workspace ~85 MB ----
    float* ws = (float*)d_ws;
    size_t off = 0;
    auto alloc = [&](size_t n) { float* p = ws + off; off += n; return p; };
    const size_t U = (size_t)N * 64;
    u16*   qkv_bf = (u16*)alloc(3 * U);        // [N,384]: phi(q)|k|v
    u16*   att_bf = (u16*)alloc(U);
    float* sbuf   = alloc((size_t)N * 128);
    float* gxs    = alloc((size_t)N * 128);
    float* xmid   = alloc((size_t)N * 128);
    u16*   ffp_bf = (u16*)alloc(U);
    u16*   ve_s   = (u16*)alloc((size_t)E * 64);   // [E,128] bf16
    float* p_arr  = alloc((size_t)E * 8);          // [E,8] fp32
    int*   e32    = (int*)alloc((size_t)2 * E);
    int*   perm   = (int*)alloc(E);
    int*   ssrc   = (int*)alloc(E);
    int*   sdst   = (int*)alloc(E);
    int*   hist   = (int*)alloc(NN);
    int*   offs   = (int*)alloc(NN + 1);
    int*   cursor = (int*)alloc(NN + 1);
    u16*   wt     = (u16*)alloc(139264);           // 278528 u16

    // transposed-weight layout (u16 element offsets into wt)
    u16* Wall_t = wt;                 // [640][128]: Wq|Wk|Wv|Ws|Wg2
    u16* Wkr_t  = wt + 81920;
    u16* Wvr_t  = wt + 98304;
    u16* Wo_t   = wt + 114688;
    u16* Wg1_t  = wt + 131072;
    u16* W1_t   = wt + 147456;        // [512][128]
    u16* W2_t   = wt + 212992;        // [128][512]

    // 0. zero histogram (one memset dispatch)
    hipMemsetAsync(hist, 0, NN * sizeof(int), stream);

    // 1. pre1: cvt+hist (blocks 0..249) + all weight transposes (250..521)
    WTArgs wa;
    int t0 = 250;
    auto setw = [&](int i, const void* w, u16* wtp, int K, int Ncol, int eoff) {
        wa.d[i] = WDesc{w, wtp, K, Ncol, eoff, t0};
        t0 += (K / 32) * (Ncol / 32);
    };
    setw(0, Wq,  wt,           128, 128, 0);
    setw(1, Wk,  wt + 16384,   128, 128, 0);
    setw(2, Wv,  wt + 32768,   128, 128, 0);
    setw(3, Ws,  wt + 49152,   128, 128, 0);
    setw(4, Wg,  wt + 65536,   128, 128, 16384);   // Wg2 = rows 128..255
    setw(5, Wkr, Wkr_t,        128, 128, 0);
    setw(6, Wvr, Wvr_t,        128, 128, 0);
    setw(7, Wo,  Wo_t,         128, 128, 0);
    setw(8, Wg,  Wg1_t,        128, 128, 0);       // Wg1 = rows 0..127
    setw(9, W1,  W1_t,         128, 512, 0);
    setw(10, W2, W2_t,         512, 128, 0);
    pre1_kernel<<<t0, 256, 0, stream>>>(ei, e32, hist, (const u16*)x, wa);

    // 2. scan, 3. scatter (dst-sort)
    scan_kernel<<<1, 256, 0, stream>>>(hist, offs, cursor);
    scatter_kernel<<<(E + 255) / 256, 256, 0, stream>>>(e32, cursor, perm, ssrc, sdst);

    // 4. node projections (LN(x) fused; qkv + sbuf + gxs in one GEMM)
    node_proj_kernel<<<N / 16, 256, 0, stream>>>(x, ln_x_g, ln_x_b, Wall_t,
                                                 bs, bg, qkv_bf, sbuf, gxs);

    // 5. edge projection (sorted, atomic-free)
    edge_proj_kernel<<<E / 32, 256, 0, stream>>>(r, x, ln_r_g, ln_r_b, Wkr_t, Wvr_t,
                                                 perm, ssrc, sdst, qkv_bf, p_arr, ve_s);

    // 6. node accumulate + normalize -> att bf16
    node_acc_kernel<<<N / 4, 256, 0, stream>>>(p_arr, ve_s, offs, att_bf);

    // 7. gate mega -> xmid, ffp
    gate_mega_kernel<<<N / 64, 256, 0, stream>>>(att_bf, Wo_t, Wg1_t, gxs, sbuf,
                                                 x, ln_po_g, ln_po_b, ln_fp_g, ln_fp_b,
                                                 xmid, ffp_bf);

    // 8. ff mega -> d_out
    ff_mega_kernel<<<N / 32, 128, 0, stream>>>(ffp_bf, W1_t, b1, W2_t, b2,
                                               xmid, x, ln_fo_g, ln_fo_b, d_out);
}

// Round 8
// 395.643 us; speedup vs baseline: 1.1816x; 1.1816x over previous
//
#include <hip/hip_runtime.h>
#include <hip/hip_bf16.h>

#define NN 16000
#define NE 128000

typedef unsigned short u16;
typedef __attribute__((ext_vector_type(8))) short bf16x8;
typedef __attribute__((ext_vector_type(4))) float f32x4;

__device__ __forceinline__ float bf2f(u16 u) {
    unsigned int v = ((unsigned int)u) << 16;
    return __uint_as_float(v);
}
__device__ __forceinline__ u16 f2bf(float f) {
    unsigned int u = __float_as_uint(f);
    unsigned int r = u + 0x7FFF + ((u >> 16) & 1);
    return (u16)(r >> 16);
}
__device__ __forceinline__ float loadf(const void* p, size_t i, int bf) {
    return bf ? bf2f(((const u16*)p)[i]) : ((const float*)p)[i];
}

// ---- per-wave dtype detect (no barrier, deterministic): bf16=1, fp32=0 -----
__device__ __forceinline__ int detect_bf(const u16* __restrict__ xw) {
    int lane = threadIdx.x & 63;
    int c = 0;
    #pragma unroll
    for (int k = 0; k < 16; ++k) {
        unsigned int w = xw[lane * 16 + k];
        int e = (int)((w >> 7) & 0xFF);
        c += (e >= 100 && e <= 140) ? 1 : 0;
    }
    for (int m = 1; m < 64; m <<= 1) c += __shfl_xor(c, m, 64);
    return c >= 850;
}

// ---- per-wave edge-index layout detect: 1 = int64, 0 = int32 ---------------
__device__ __forceinline__ int detect_e64(const int* __restrict__ ei) {
    int lane = threadIdx.x & 63;
    int a = 0;
    #pragma unroll
    for (int k = 0; k < 16; ++k) a |= ei[2 * (lane * 16 + k) + 1];
    for (int m = 1; m < 64; m <<= 1) a |= __shfl_xor(a, m, 64);
    return a == 0;
}

// ---- pre1: blocks [0,250) cvt+clamp+hist; blocks [250,522) weight transpose
struct WDesc { const void* w; u16* wt; int K; int N; int off; int tile0; };
struct WTArgs { WDesc d[11]; };
__global__ __launch_bounds__(256) void pre1_kernel(const int* __restrict__ ei,
                                                   int* __restrict__ e32,
                                                   int* __restrict__ hist,
                                                   const u16* __restrict__ xw,
                                                   WTArgs args)
{
    int b = blockIdx.x;
    int tid = threadIdx.x;
    if (b < 250) {
        int e64 = detect_e64(ei);
        #pragma unroll
        for (int j = 0; j < 4; ++j) {
            int i = b * 1024 + j * 256 + tid;      // [0, 2E)
            int v = e64 ? ei[2 * i] : ei[i];
            v = v < 0 ? 0 : (v >= NN ? NN - 1 : v);
            e32[i] = v;
            if (i >= NE) atomicAdd(&hist[v], 1);
        }
        return;
    }
    int bf = detect_bf(xw);
    int i = 0;
    while (i < 10 && b >= args.d[i + 1].tile0) ++i;
    WDesc de = args.d[i];
    int lt = b - de.tile0;
    int tn = de.N >> 5;
    int tk = lt / tn, tc = lt % tn;
    int n = tc * 32 + (tid & 31);
    int k = tk * 32 + ((tid >> 5) << 2);
    u16* dp = de.wt + (size_t)n * de.K + k;
    #pragma unroll
    for (int j = 0; j < 4; ++j)
        dp[j] = f2bf(loadf(de.w, (size_t)de.off + (size_t)(k + j) * de.N + n, bf));
}

// ---- exclusive scan of hist -> offs[NN+1], cursor; 4 elems/thread ----------
__global__ __launch_bounds__(256) void scan_kernel(const int* __restrict__ hist,
                                                   int* __restrict__ offs,
                                                   int* __restrict__ cursor)
{
    __shared__ int wsum[4];
    __shared__ int carry_s;
    int tid = threadIdx.x, lane = tid & 63, w = tid >> 6;
    if (tid == 0) { carry_s = 0; offs[0] = 0; cursor[0] = 0; }
    __syncthreads();
    for (int c0 = 0; c0 < NN; c0 += 1024) {
        int i0 = c0 + tid * 4;
        int a0 = (i0 + 0 < NN) ? hist[i0 + 0] : 0;
        int a1 = (i0 + 1 < NN) ? hist[i0 + 1] : 0;
        int a2 = (i0 + 2 < NN) ? hist[i0 + 2] : 0;
        int a3 = (i0 + 3 < NN) ? hist[i0 + 3] : 0;
        int s_loc = a0 + a1 + a2 + a3;
        int x = s_loc;
        #pragma unroll
        for (int o = 1; o < 64; o <<= 1) {
            int y = __shfl_up(x, o, 64);
            if (lane >= o) x += y;
        }
        if (lane == 63) wsum[w] = x;
        __syncthreads();
        if (tid == 0) {
            int s = 0;
            #pragma unroll
            for (int j = 0; j < 4; ++j) { int t2 = wsum[j]; wsum[j] = s; s += t2; }
        }
        __syncthreads();
        int excl = x - s_loc + wsum[w] + carry_s;
        int p0 = excl + a0, p1 = p0 + a1, p2 = p1 + a2, p3 = p2 + a3;
        if (i0 + 0 < NN) { offs[i0 + 1] = p0; cursor[i0 + 1] = p0; }
        if (i0 + 1 < NN) { offs[i0 + 2] = p1; cursor[i0 + 2] = p1; }
        if (i0 + 2 < NN) { offs[i0 + 3] = p2; cursor[i0 + 3] = p2; }
        if (i0 + 3 < NN) { offs[i0 + 4] = p3; cursor[i0 + 4] = p3; }
        __syncthreads();
        if (tid == 255) carry_s = p3;
        __syncthreads();
    }
}

// ---- scatter: dst-sorted edge order ----------------------------------------
__global__ void scatter_kernel(const int* __restrict__ e32, int* __restrict__ cursor,
                               int* __restrict__ perm, int* __restrict__ ssrc,
                               int* __restrict__ sdst)
{
    int i = blockIdx.x * 256 + threadIdx.x;
    if (i >= NE) return;
    int d = e32[NE + i];
    int pos = atomicAdd(&cursor[d], 1);
    perm[pos] = i;
    ssrc[pos] = e32[i];
    sdst[pos] = d;
}

// ---- node_proj mega: LN(x) in-reg -> GEMM vs [Wq|Wk|Wv|Ws|Wg2] (640 cols) --
__global__ __launch_bounds__(256) void node_proj_kernel(
    const void* __restrict__ x,
    const void* __restrict__ lng, const void* __restrict__ lnb,
    const u16* __restrict__ Wall,
    const void* __restrict__ bs, const void* __restrict__ bg,
    u16* __restrict__ qkv, float* __restrict__ sbuf, float* __restrict__ gxs)
{
    const int bf = detect_bf((const u16*)x);
    __shared__ float sg[128], sb[128];
    int tid = threadIdx.x;
    if (tid < 128) { sg[tid] = loadf(lng, tid, bf); sb[tid] = loadf(lnb, tid, bf); }
    __syncthreads();
    int wave = tid >> 6, lane = tid & 63;
    int quad = lane >> 4, l15 = lane & 15;
    int m0 = blockIdx.x * 16;

    float vbuf[32];
    float s = 0.f, sq = 0.f;
    size_t rbase = (size_t)(m0 + l15) * 128;
    #pragma unroll
    for (int kc = 0; kc < 4; ++kc) {
        int cb = kc * 32 + quad * 8;
        if (bf) {
            ushort4 p0 = *(const ushort4*)((const u16*)x + rbase + cb);
            ushort4 p1 = *(const ushort4*)((const u16*)x + rbase + cb + 4);
            vbuf[kc*8+0]=bf2f(p0.x); vbuf[kc*8+1]=bf2f(p0.y); vbuf[kc*8+2]=bf2f(p0.z); vbuf[kc*8+3]=bf2f(p0.w);
            vbuf[kc*8+4]=bf2f(p1.x); vbuf[kc*8+5]=bf2f(p1.y); vbuf[kc*8+6]=bf2f(p1.z); vbuf[kc*8+7]=bf2f(p1.w);
        } else {
            float4 p0 = *(const float4*)((const float*)x + rbase + cb);
            float4 p1 = *(const float4*)((const float*)x + rbase + cb + 4);
            vbuf[kc*8+0]=p0.x; vbuf[kc*8+1]=p0.y; vbuf[kc*8+2]=p0.z; vbuf[kc*8+3]=p0.w;
            vbuf[kc*8+4]=p1.x; vbuf[kc*8+5]=p1.y; vbuf[kc*8+6]=p1.z; vbuf[kc*8+7]=p1.w;
        }
        #pragma unroll
        for (int j = 0; j < 8; ++j) { s += vbuf[kc*8+j]; sq += vbuf[kc*8+j]*vbuf[kc*8+j]; }
    }
    s += __shfl_xor(s, 16, 64); sq += __shfl_xor(sq, 16, 64);
    s += __shfl_xor(s, 32, 64); sq += __shfl_xor(sq, 32, 64);
    float mu = s * (1.0f / 128.0f);
    float var = sq * (1.0f / 128.0f) - mu * mu;
    float rsx = rsqrtf(var + 1e-5f);
    bf16x8 afr[4];
    #pragma unroll
    for (int kc = 0; kc < 4; ++kc) {
        bf16x8 a;
        #pragma unroll
        for (int j = 0; j < 8; ++j) {
            int col = kc * 32 + quad * 8 + j;
            a[j] = (short)f2bf((vbuf[kc*8+j] - mu) * rsx * sg[col] + sb[col]);
        }
        afr[kc] = a;
    }

    f32x4 acc[10] = {};
    #pragma unroll
    for (int kc = 0; kc < 4; ++kc)
        #pragma unroll
        for (int tt = 0; tt < 10; ++tt) {
            int t = wave * 10 + tt;
            bf16x8 b = *(const bf16x8*)(Wall + (size_t)(t * 16 + l15) * 128 + kc * 32 + quad * 8);
            acc[tt] = __builtin_amdgcn_mfma_f32_16x16x32_bf16(afr[kc], b, acc[tt], 0, 0, 0);
        }
    #pragma unroll
    for (int tt = 0; tt < 10; ++tt) {
        int ct = (wave * 10 + tt) * 16 + l15;
        #pragma unroll
        for (int rg = 0; rg < 4; ++rg) {
            int row = m0 + quad * 4 + rg;
            float v = acc[tt][rg];
            if (ct < 384) {
                if (ct < 128) v = (v > 0.0f) ? v + 1.0f : expf(v);
                qkv[(size_t)row * 384 + ct] = f2bf(v);
            } else if (ct < 512) {
                int cs = ct - 384;
                sbuf[(size_t)row * 128 + cs] = v + loadf(bs, cs, bf);
            } else {
                int cg = ct - 512;
                gxs[(size_t)row * 128 + cg] = v + loadf(bg, cg, bf);
            }
        }
    }
}

// ---- Edge proj (dst-sorted, atomic-free) -----------------------------------
__global__ __launch_bounds__(256) void edge_proj_kernel(
    const void* __restrict__ r, const void* __restrict__ x,
    const void* __restrict__ lng, const void* __restrict__ lnb,
    const u16* __restrict__ Wkrt, const u16* __restrict__ Wvrt,
    const int* __restrict__ perm, const int* __restrict__ ssrc,
    const int* __restrict__ sdst,
    const u16* __restrict__ qkv,
    float* __restrict__ p_arr, u16* __restrict__ ve_s)
{
    const int bf = detect_bf((const u16*)x);
    __shared__ float sg[128], sb[128];
    int tid = threadIdx.x;
    if (tid < 128) { sg[tid] = loadf(lng, tid, bf); sb[tid] = loadf(lnb, tid, bf); }
    __syncthreads();
    int wave = tid >> 6, lane = tid & 63;
    int quad = lane >> 4, l15 = lane & 15;
    int e0 = blockIdx.x * 32 + (wave >> 1) * 16;
    int c0 = (wave & 1) * 64;

    int rrow = perm[e0 + l15];
    float vbuf[32];
    float s = 0.f, sq = 0.f;
    size_t rbase = (size_t)rrow * 128;
    #pragma unroll
    for (int kc = 0; kc < 4; ++kc) {
        int cb = kc * 32 + quad * 8;
        if (bf) {
            ushort4 p0 = *(const ushort4*)((const u16*)r + rbase + cb);
            ushort4 p1 = *(const ushort4*)((const u16*)r + rbase + cb + 4);
            vbuf[kc*8+0]=bf2f(p0.x); vbuf[kc*8+1]=bf2f(p0.y); vbuf[kc*8+2]=bf2f(p0.z); vbuf[kc*8+3]=bf2f(p0.w);
            vbuf[kc*8+4]=bf2f(p1.x); vbuf[kc*8+5]=bf2f(p1.y); vbuf[kc*8+6]=bf2f(p1.z); vbuf[kc*8+7]=bf2f(p1.w);
        } else {
            float4 p0 = *(const float4*)((const float*)r + rbase + cb);
            float4 p1 = *(const float4*)((const float*)r + rbase + cb + 4);
            vbuf[kc*8+0]=p0.x; vbuf[kc*8+1]=p0.y; vbuf[kc*8+2]=p0.z; vbuf[kc*8+3]=p0.w;
            vbuf[kc*8+4]=p1.x; vbuf[kc*8+5]=p1.y; vbuf[kc*8+6]=p1.z; vbuf[kc*8+7]=p1.w;
        }
        #pragma unroll
        for (int j = 0; j < 8; ++j) { s += vbuf[kc*8+j]; sq += vbuf[kc*8+j]*vbuf[kc*8+j]; }
    }
    s += __shfl_xor(s, 16, 64); sq += __shfl_xor(sq, 16, 64);
    s += __shfl_xor(s, 32, 64); sq += __shfl_xor(sq, 32, 64);
    float mu = s * (1.0f / 128.0f);
    float var = sq * (1.0f / 128.0f) - mu * mu;
    float rsx = rsqrtf(var + 1e-5f);
    bf16x8 afr[4];
    #pragma unroll
    for (int kc = 0; kc < 4; ++kc) {
        bf16x8 a;
        #pragma unroll
        for (int j = 0; j < 8; ++j) {
            int col = kc * 32 + quad * 8 + j;
            a[j] = (short)f2bf((vbuf[kc*8+j] - mu) * rsx * sg[col] + sb[col]);
        }
        afr[kc] = a;
    }

    f32x4 acck[4] = {};
    f32x4 accv[4] = {};
    #pragma unroll
    for (int kc = 0; kc < 4; ++kc) {
        int k0 = kc * 32;
        #pragma unroll
        for (int t = 0; t < 4; ++t) {
            bf16x8 bk = *(const bf16x8*)(Wkrt + (size_t)(c0 + t*16 + l15) * 128 + k0 + quad * 8);
            bf16x8 bv = *(const bf16x8*)(Wvrt + (size_t)(c0 + t*16 + l15) * 128 + k0 + quad * 8);
            acck[t] = __builtin_amdgcn_mfma_f32_16x16x32_bf16(afr[kc], bk, acck[t], 0, 0, 0);
            accv[t] = __builtin_amdgcn_mfma_f32_16x16x32_bf16(afr[kc], bv, accv[t], 0, 0, 0);
        }
    }

    int se[4], de[4];
    #pragma unroll
    for (int rg = 0; rg < 4; ++rg) {
        int e = e0 + quad * 4 + rg;
        se[rg] = ssrc[e]; de[rg] = sdst[e];
    }
    #pragma unroll
    for (int t = 0; t < 4; ++t) {
        int col = c0 + t * 16 + l15;
        float p_[4];
        #pragma unroll
        for (int rg = 0; rg < 4; ++rg) {
            float kv = acck[t][rg] + bf2f(qkv[(size_t)se[rg] * 384 + 128 + col]);
            kv = (kv > 0.0f) ? kv + 1.0f : expf(kv);
            float pm = kv * bf2f(qkv[(size_t)de[rg] * 384 + col]);
            pm += __shfl_xor(pm, 1, 64);
            pm += __shfl_xor(pm, 2, 64);
            pm += __shfl_xor(pm, 4, 64);
            pm += __shfl_xor(pm, 8, 64);
            p_[rg] = pm;
        }
        if (l15 == 0) {
            #pragma unroll
            for (int rg = 0; rg < 4; ++rg)
                p_arr[(size_t)(e0 + quad * 4 + rg) * 8 + (c0 >> 4) + t] = p_[rg];
        }
        #pragma unroll
        for (int rg = 0; rg < 4; ++rg) {
            float vv = accv[t][rg] + bf2f(qkv[(size_t)se[rg] * 384 + 256 + col]);
            ve_s[(size_t)(e0 + quad * 4 + rg) * 128 + col] = f2bf(vv);
        }
    }
}

// ---- Node accumulate: att(fp32) = (sum p*ve)/max(sum p,eps); 4B loads ------
__global__ __launch_bounds__(256) void node_acc_kernel(
    const float* __restrict__ p_arr, const u16* __restrict__ ve_s,
    const int* __restrict__ offs, float* __restrict__ att)
{
    int n = blockIdx.x * 4 + (threadIdx.x >> 6);
    int lane = threadIdx.x & 63;
    int beg = offs[n], end = offs[n + 1];
    int h = lane >> 3;                 // cols 2*lane, 2*lane+1 (same head)
    float na0 = 0.f, na1 = 0.f, da = 0.f;
    float nb0 = 0.f, nb1 = 0.f, db = 0.f;
    int e = beg;
    for (; e + 1 < end; e += 2) {
        float pa = p_arr[(size_t)e * 8 + h];
        float pb = p_arr[(size_t)(e + 1) * 8 + h];
        ushort2 va = *(const ushort2*)&ve_s[(size_t)e * 128 + 2 * lane];
        ushort2 vb = *(const ushort2*)&ve_s[(size_t)(e + 1) * 128 + 2 * lane];
        na0 += pa * bf2f(va.x); na1 += pa * bf2f(va.y); da += pa;
        nb0 += pb * bf2f(vb.x); nb1 += pb * bf2f(vb.y); db += pb;
    }
    if (e < end) {
        float pa = p_arr[(size_t)e * 8 + h];
        ushort2 va = *(const ushort2*)&ve_s[(size_t)e * 128 + 2 * lane];
        na0 += pa * bf2f(va.x); na1 += pa * bf2f(va.y); da += pa;
    }
    float inv = 1.0f / fmaxf(da + db, 1e-6f);
    att[(size_t)n * 128 + 2 * lane]     = (na0 + nb0) * inv;
    att[(size_t)n * 128 + 2 * lane + 1] = (na1 + nb1) * inv;
}

// ---- Gate mega: att(fp32, hi/lo MFMA)@Wo -> @Wg1(+gxs) -> gate -> post-LN ---
__global__ __launch_bounds__(256) void gate_mega_kernel(
    const float* __restrict__ att,
    const u16* __restrict__ Wo_t, const u16* __restrict__ Wg1_t,
    const float* __restrict__ gxs, const float* __restrict__ sbuf,
    const void* __restrict__ x,
    const void* __restrict__ g_po, const void* __restrict__ b_po,
    const void* __restrict__ g_fp, const void* __restrict__ b_fp,
    float* __restrict__ xmid, u16* __restrict__ ffp)
{
    const int bf = detect_bf((const u16*)x);
    __shared__ float lds[4][16][132];
    __shared__ float sgpo[128], sbpo[128], sgfp[128], sbfp[128];
    int tid = threadIdx.x;
    if (tid < 128) {
        sgpo[tid] = loadf(g_po, tid, bf);
        sbpo[tid] = loadf(b_po, tid, bf);
        sgfp[tid] = loadf(g_fp, tid, bf);
        sbfp[tid] = loadf(b_fp, tid, bf);
    }
    __syncthreads();
    int wave = tid >> 6, lane = tid & 63;
    int quad = lane >> 4, l15 = lane & 15;
    int m0 = blockIdx.x * 64 + wave * 16;

    // att fragments in double-bf16 (hi + lo)
    bf16x8 ahi[4], alo[4];
    #pragma unroll
    for (int kc = 0; kc < 4; ++kc) {
        const float* ap = att + (size_t)(m0 + l15) * 128 + kc * 32 + quad * 8;
        float4 v0 = *(const float4*)ap;
        float4 v1 = *(const float4*)(ap + 4);
        float vv[8] = {v0.x, v0.y, v0.z, v0.w, v1.x, v1.y, v1.z, v1.w};
        bf16x8 h, l;
        #pragma unroll
        for (int j = 0; j < 8; ++j) {
            u16 hb = f2bf(vv[j]);
            h[j] = (short)hb;
            l[j] = (short)f2bf(vv[j] - bf2f(hb));
        }
        ahi[kc] = h; alo[kc] = l;
    }
    f32x4 acco[8] = {};
    #pragma unroll
    for (int kc = 0; kc < 4; ++kc)
        #pragma unroll
        for (int t = 0; t < 8; ++t) {
            bf16x8 b = *(const bf16x8*)(Wo_t + (size_t)(t*16 + l15) * 128 + kc*32 + quad*8);
            acco[t] = __builtin_amdgcn_mfma_f32_16x16x32_bf16(ahi[kc], b, acco[t], 0, 0, 0);
            acco[t] = __builtin_amdgcn_mfma_f32_16x16x32_bf16(alo[kc], b, acco[t], 0, 0, 0);
        }
    #pragma unroll
    for (int t = 0; t < 8; ++t)
        #pragma unroll
        for (int rg = 0; rg < 4; ++rg)
            lds[wave][quad*4+rg][t*16+l15] = acco[t][rg];
    __syncthreads();
    bf16x8 afo[4];
    #pragma unroll
    for (int kc = 0; kc < 4; ++kc) {
        bf16x8 a;
        #pragma unroll
        for (int j = 0; j < 8; ++j)
            a[j] = (short)f2bf(lds[wave][l15][kc*32 + quad*8 + j]);
        afo[kc] = a;
    }
    f32x4 accg[8] = {};
    #pragma unroll
    for (int kc = 0; kc < 4; ++kc)
        #pragma unroll
        for (int t = 0; t < 8; ++t) {
            bf16x8 b = *(const bf16x8*)(Wg1_t + (size_t)(t*16 + l15) * 128 + kc*32 + quad*8);
            accg[t] = __builtin_amdgcn_mfma_f32_16x16x32_bf16(afo[kc], b, accg[t], 0, 0, 0);
        }
    float attn[8][4];
    float sv[4] = {0,0,0,0}, sqv[4] = {0,0,0,0};
    #pragma unroll
    for (int t = 0; t < 8; ++t) {
        int col = t * 16 + l15;
        #pragma unroll
        for (int rg = 0; rg < 4; ++rg) {
            int row = m0 + quad * 4 + rg;
            float gp = accg[t][rg] + gxs[(size_t)row * 128 + col];
            float gg = 1.0f / (1.0f + expf(-gp));
            float o = acco[t][rg];
            float a = o + gg * (sbuf[(size_t)row * 128 + col] - o);
            attn[t][rg] = a; sv[rg] += a; sqv[rg] += a * a;
        }
    }
    #pragma unroll
    for (int rg = 0; rg < 4; ++rg)
        for (int m = 1; m < 16; m <<= 1) {
            sv[rg] += __shfl_xor(sv[rg], m, 64);
            sqv[rg] += __shfl_xor(sqv[rg], m, 64);
        }
    float mu[4], rs[4];
    #pragma unroll
    for (int rg = 0; rg < 4; ++rg) {
        mu[rg] = sv[rg] * (1.0f / 128.0f);
        float var = sqv[rg] * (1.0f / 128.0f) - mu[rg] * mu[rg];
        rs[rg] = rsqrtf(var + 1e-5f);
    }
    float s2[4] = {0,0,0,0}, sq2[4] = {0,0,0,0};
    #pragma unroll
    for (int t = 0; t < 8; ++t) {
        int col = t * 16 + l15;
        #pragma unroll
        for (int rg = 0; rg < 4; ++rg) {
            int row = m0 + quad * 4 + rg;
            float xm = loadf(x, (size_t)row * 128 + col, bf)
                     + (attn[t][rg] - mu[rg]) * rs[rg] * sgpo[col] + sbpo[col];
            attn[t][rg] = xm;
            xmid[(size_t)row * 128 + col] = xm;
            s2[rg] += xm; sq2[rg] += xm * xm;
        }
    }
    #pragma unroll
    for (int rg = 0; rg < 4; ++rg)
        for (int m = 1; m < 16; m <<= 1) {
            s2[rg] += __shfl_xor(s2[rg], m, 64);
            sq2[rg] += __shfl_xor(sq2[rg], m, 64);
        }
    #pragma unroll
    for (int rg = 0; rg < 4; ++rg) {
        float mu2 = s2[rg] * (1.0f / 128.0f);
        float var2 = sq2[rg] * (1.0f / 128.0f) - mu2 * mu2;
        float rs2 = rsqrtf(var2 + 1e-5f);
        #pragma unroll
        for (int t = 0; t < 8; ++t) {
            int col = t * 16 + l15;
            int row = m0 + quad * 4 + rg;
            ffp[(size_t)row * 128 + col] =
                f2bf((attn[t][rg] - mu2) * rs2 * sgfp[col] + sbfp[col]);
        }
    }
}

// ---- FF mega v2: split-K across 4 waves, 16 rows/block ---------------------
__global__ __launch_bounds__(256) void ff_mega_kernel(
    const u16* __restrict__ ffp, const u16* __restrict__ W1_t, const void* __restrict__ b1,
    const u16* __restrict__ W2_t, const void* __restrict__ b2,
    const float* __restrict__ xmid, const void* __restrict__ x,
    const void* __restrict__ g_fo, const void* __restrict__ b_fo,
    void* __restrict__ outp)
{
    const int bf = detect_bf((const u16*)x);
    __shared__ __align__(16) u16 h1l[16][520];
    __shared__ float psum[4][16], psq[4][16];
    int tid = threadIdx.x;
    int wave = tid >> 6, lane = tid & 63;
    int quad = lane >> 4, l15 = lane & 15;
    int m0 = blockIdx.x * 16;

    bf16x8 afr[4];
    const u16* ap = ffp + (size_t)(m0 + l15) * 128 + quad * 8;
    #pragma unroll
    for (int kc = 0; kc < 4; ++kc) afr[kc] = *(const bf16x8*)(ap + kc * 32);

    // stage 1: wave w -> h1 cols [w*128, w*128+128)
    f32x4 acc1[8] = {};
    #pragma unroll
    for (int kc = 0; kc < 4; ++kc)
        #pragma unroll
        for (int tt = 0; tt < 8; ++tt) {
            int t = wave * 8 + tt;
            bf16x8 b = *(const bf16x8*)(W1_t + (size_t)(t*16 + l15) * 128 + kc*32 + quad*8);
            acc1[tt] = __builtin_amdgcn_mfma_f32_16x16x32_bf16(afr[kc], b, acc1[tt], 0, 0, 0);
        }
    #pragma unroll
    for (int tt = 0; tt < 8; ++tt) {
        int col = (wave * 8 + tt) * 16 + l15;
        float bv = loadf(b1, col, bf);
        #pragma unroll
        for (int rg = 0; rg < 4; ++rg) {
            float v = acc1[tt][rg] + bv;
            v = 0.5f * v * (1.0f + erff(v * 0.70710678118f));
            h1l[quad * 4 + rg][col] = f2bf(v);
        }
    }
    __syncthreads();
    // stage 2: wave w -> h2 col tiles {2w, 2w+1}
    f32x4 acc2[2] = {};
    #pragma unroll
    for (int kc = 0; kc < 16; ++kc) {
        bf16x8 a = *(const bf16x8*)&h1l[l15][kc * 32 + quad * 8];
        #pragma unroll
        for (int tt = 0; tt < 2; ++tt) {
            int t = wave * 2 + tt;
            bf16x8 b = *(const bf16x8*)(W2_t + (size_t)(t*16 + l15) * 512 + kc*32 + quad*8);
            acc2[tt] = __builtin_amdgcn_mfma_f32_16x16x32_bf16(a, b, acc2[tt], 0, 0, 0);
        }
    }
    float h2v[2][4];
    float sv[4] = {0,0,0,0}, sqv[4] = {0,0,0,0};
    #pragma unroll
    for (int tt = 0; tt < 2; ++tt) {
        int col = (wave * 2 + tt) * 16 + l15;
        float bv = loadf(b2, col, bf);
        #pragma unroll
        for (int rg = 0; rg < 4; ++rg) {
            float v = acc2[tt][rg] + bv;
            h2v[tt][rg] = v; sv[rg] += v; sqv[rg] += v * v;
        }
    }
    #pragma unroll
    for (int rg = 0; rg < 4; ++rg)
        for (int m = 1; m < 16; m <<= 1) {
            sv[rg] += __shfl_xor(sv[rg], m, 64);
            sqv[rg] += __shfl_xor(sqv[rg], m, 64);
        }
    if (l15 == 0) {
        #pragma unroll
        for (int rg = 0; rg < 4; ++rg) {
            psum[wave][quad * 4 + rg] = sv[rg];
            psq[wave][quad * 4 + rg]  = sqv[rg];
        }
    }
    __syncthreads();
    #pragma unroll
    for (int rg = 0; rg < 4; ++rg) {
        int rl = quad * 4 + rg;
        float ts = psum[0][rl] + psum[1][rl] + psum[2][rl] + psum[3][rl];
        float tq = psq[0][rl]  + psq[1][rl]  + psq[2][rl]  + psq[3][rl];
        float mu = ts * (1.0f / 128.0f);
        float var = tq * (1.0f / 128.0f) - mu * mu;
        float rs = rsqrtf(var + 1e-5f);
        int row = m0 + rl;
        #pragma unroll
        for (int tt = 0; tt < 2; ++tt) {
            int col = (wave * 2 + tt) * 16 + l15;
            float y = xmid[(size_t)row * 128 + col]
                    + (h2v[tt][rg] - mu) * rs * loadf(g_fo, col, bf) + loadf(b_fo, col, bf);
            if (bf) ((u16*)outp)[(size_t)row * 128 + col] = f2bf(y);
            else    ((float*)outp)[(size_t)row * 128 + col] = y;
        }
    }
}

extern "C" void kernel_launch(void* const* d_in, const int* in_sizes, int n_in,
                              void* d_out, int out_size, void* d_ws, size_t ws_size,
                              hipStream_t stream)
{
    const int N = NN, E = NE;
    const void* x       = d_in[0];
    const void* r       = d_in[1];
    const int*  ei      = (const int*)d_in[2];
    const void* ln_x_g  = d_in[3];
    const void* ln_x_b  = d_in[4];
    const void* ln_r_g  = d_in[5];
    const void* ln_r_b  = d_in[6];
    const void* ln_po_g = d_in[7];
    const void* ln_po_b = d_in[8];
    const void* ln_fp_g = d_in[9];
    const void* ln_fp_b = d_in[10];
    const void* ln_fo_g = d_in[11];
    const void* ln_fo_b = d_in[12];
    const void* Wq      = d_in[13];
    const void* Wk      = d_in[14];
    const void* Wv      = d_in[15];
    const void* Wkr     = d_in[16];
    const void* Wvr     = d_in[17];
    const void* Wo      = d_in[18];
    const void* Wg      = d_in[19];
    const void* bg      = d_in[20];
    const void* Ws      = d_in[21];
    const void* bs      = d_in[22];
    const void* W1      = d_in[23];
    const void* b1      = d_in[24];
    const void* W2      = d_in[25];
    const void* b2      = d_in[26];

    // ---- workspace ~90 MB ----
    float* ws = (float*)d_ws;
    size_t off = 0;
    auto alloc = [&](size_t n) { float* p = ws + off; off += n; return p; };
    const size_t U = (size_t)N * 64;
    u16*   qkv_bf = (u16*)alloc(3 * U);        // [N,384]: phi(q)|k|v
    float* att    = alloc((size_t)N * 128);    // fp32
    float* sbuf   = alloc((size_t)N * 128);
    float* gxs    = alloc((size_t)N * 128);
    float* xmid   = alloc((size_t)N * 128);
    u16*   ffp_bf = (u16*)alloc(U);
    u16*   ve_s   = (u16*)alloc((size_t)E * 64);   // [E,128] bf16
    float* p_arr  = alloc((size_t)E * 8);          // [E,8] fp32
    int*   e32    = (int*)alloc((size_t)2 * E);
    int*   perm   = (int*)alloc(E);
    int*   ssrc   = (int*)alloc(E);
    int*   sdst   = (int*)alloc(E);
    int*   hist   = (int*)alloc(NN);
    int*   offs   = (int*)alloc(NN + 1);
    int*   cursor = (int*)alloc(NN + 1);
    u16*   wt     = (u16*)alloc(139264);           // 278528 u16

    u16* Wall_t = wt;                 // [640][128]: Wq|Wk|Wv|Ws|Wg2
    u16* Wkr_t  = wt + 81920;
    u16* Wvr_t  = wt + 98304;
    u16* Wo_t   = wt + 114688;
    u16* Wg1_t  = wt + 131072;
    u16* W1_t   = wt + 147456;        // [512][128]
    u16* W2_t   = wt + 212992;        // [128][512]

    hipMemsetAsync(hist, 0, NN * sizeof(int), stream);

    WTArgs wa;
    int t0 = 250;
    auto setw = [&](int i, const void* w, u16* wtp, int K, int Ncol, int eoff) {
        wa.d[i] = WDesc{w, wtp, K, Ncol, eoff, t0};
        t0 += (K / 32) * (Ncol / 32);
    };
    setw(0, Wq,  wt,           128, 128, 0);
    setw(1, Wk,  wt + 16384,   128, 128, 0);
    setw(2, Wv,  wt + 32768,   128, 128, 0);
    setw(3, Ws,  wt + 49152,   128, 128, 0);
    setw(4, Wg,  wt + 65536,   128, 128, 16384);   // Wg2 = rows 128..255
    setw(5, Wkr, Wkr_t,        128, 128, 0);
    setw(6, Wvr, Wvr_t,        128, 128, 0);
    setw(7, Wo,  Wo_t,         128, 128, 0);
    setw(8, Wg,  Wg1_t,        128, 128, 0);       // Wg1 = rows 0..127
    setw(9, W1,  W1_t,         128, 512, 0);
    setw(10, W2, W2_t,         512, 128, 0);
    pre1_kernel<<<t0, 256, 0, stream>>>(ei, e32, hist, (const u16*)x, wa);

    scan_kernel<<<1, 256, 0, stream>>>(hist, offs, cursor);
    scatter_kernel<<<(E + 255) / 256, 256, 0, stream>>>(e32, cursor, perm, ssrc, sdst);

    node_proj_kernel<<<N / 16, 256, 0, stream>>>(x, ln_x_g, ln_x_b, Wall_t,
                                                 bs, bg, qkv_bf, sbuf, gxs);

    edge_proj_kernel<<<E / 32, 256, 0, stream>>>(r, x, ln_r_g, ln_r_b, Wkr_t, Wvr_t,
                                                 perm, ssrc, sdst, qkv_bf, p_arr, ve_s);

    node_acc_kernel<<<N / 4, 256, 0, stream>>>(p_arr, ve_s, offs, att);

    gate_mega_kernel<<<N / 64, 256, 0, stream>>>(att, Wo_t, Wg1_t, gxs, sbuf,
                                                 x, ln_po_g, ln_po_b, ln_fp_g, ln_fp_b,
                                                 xmid, ffp_bf);

    ff_mega_kernel<<<N / 16, 256, 0, stream>>>(ffp_bf, W1_t, b1, W2_t, b2,
                                               xmid, x, ln_fo_g, ln_fo_b, d_out);
}